// Round 11
// baseline (112.401 us; speedup 1.0000x reference)
//
#include <hip/hip_runtime.h>

#define BDIM 2
#define SDIM 4096
#define HIDDEN 2048
#define NH 4
#define DD 64
#define RR 32
constexpr float LN_EPS = 1e-5f;

typedef _Float16 half8 __attribute__((ext_vector_type(8)));   // 8 f16 = 4 VGPRs
typedef __attribute__((ext_vector_type(4))) float f32x4;

// async global -> LDS, 16 B per lane (wave-uniform LDS base + lane*16)
__device__ __forceinline__ void gload_lds16(const void* g, void* l) {
    __builtin_amdgcn_global_load_lds(
        (const __attribute__((address_space(1))) void*)g,
        (__attribute__((address_space(3))) void*)l, 16, 0, 0);
}

// ---------------------------------------------------------------------------
// prep_w2 (R6 map): Wt2 f16 [384][2048] transposed k-contiguous, pre-swizzled
// (16B-slot XOR with row&7). n-order: q 0..255, k 256..319, w 320..323,
// zeros to 383. Grid (32, 6), 256 threads.
// ---------------------------------------------------------------------------
__global__ __launch_bounds__(256) void prep_w2(
    const float* __restrict__ Wq, const float* __restrict__ Wk,
    const float* __restrict__ Ww, _Float16* __restrict__ Wt2)
{
    __shared__ float T[64][65];
    const int k0 = blockIdx.x * 64, n0 = blockIdx.y * 64;
    const int tid = threadIdx.x;
    {
        const int kr = tid >> 2;
        const int nq = (tid & 3) * 16;
        const int gk = k0 + kr;
        #pragma unroll
        for (int c = 0; c < 16; ++c) {
            const int n = n0 + nq + c;
            float v;
            if (n < 256)      v = Wq[(size_t)gk * 256 + n];
            else if (n < 320) v = Wk[(size_t)gk * 64 + (n - 256)];
            else if (n < 324) v = Ww[(size_t)gk * NH + (n - 320)];
            else              v = 0.f;
            T[kr][nq + c] = v;
        }
    }
    __syncthreads();
    {
        const int nr = tid >> 2;
        const int kc = (tid & 3) * 16;
        const int n  = n0 + nr;
        #pragma unroll
        for (int s = 0; s < 2; ++s) {
            const int kb = kc + s * 8;
            _Float16 e[8];
            #pragma unroll
            for (int t = 0; t < 8; ++t) e[t] = (_Float16)T[kb + t][nr];
            const int eoff = (k0 + kb) ^ ((nr & 7) << 3);
            *reinterpret_cast<half8*>(&Wt2[(size_t)n * HIDDEN + eoff]) =
                *reinterpret_cast<half8*>(e);
        }
    }
}

// ---------------------------------------------------------------------------
// proj_mfma v5: A-operand DIRECT from hs f32 (no LDS, no split_hs pass) —
// each lane loads 8 consecutive f32 of its fragment row and RTE-casts to f16
// (bit-identical to the old split_hs+LDS path). B stays gload_lds+swizzle
// (shared across waves). 128M x 64N, BK=128, grid (64,6), 4 waves of 32x64,
// 16 KB LDS. Epilogue identical to the measured-good R10 version.
// ---------------------------------------------------------------------------
__global__ __launch_bounds__(256) void proj_mfma(
    const float* __restrict__ hs, const _Float16* __restrict__ Wt2,
    const float* __restrict__ cosb, const float* __restrict__ sinb,
    const float* __restrict__ gamma, const float* __restrict__ beta,
    _Float16* __restrict__ qout, _Float16* __restrict__ kout,
    float* __restrict__ wout)
{
    __shared__ _Float16 Bsm[64 * 128];    // 16 KB

    const int m0   = blockIdx.x * 128;
    const int ng   = blockIdx.y;
    const int tid  = threadIdx.x;
    const int wave = tid >> 6, lane = tid & 63;
    const int lr = lane & 15, lh = lane >> 4;

    f32x4 acc[2][4];
    #pragma unroll
    for (int i = 0; i < 2; ++i)
        #pragma unroll
        for (int j = 0; j < 4; ++j)
            acc[i][j] = (f32x4){0.f, 0.f, 0.f, 0.f};

    // B staging (R10 pattern): thread t covers row t>>4 (+16/inst), slot t&15
    const int srow  = tid >> 4;
    const int sslot = tid & 15;
    const _Float16* gB = Wt2 + (size_t)(ng * 64 + srow) * HIDDEN + sslot * 8;
    _Float16* lB = Bsm + tid * 8;

    // A direct-load base: this lane's fragment rows start at m0+wave*32+lr
    const float* gA = hs + (size_t)(m0 + wave * 32 + lr) * HIDDEN + lh * 8;

    for (int k0 = 0; k0 < HIDDEN; k0 += 128) {
        #pragma unroll
        for (int i = 0; i < 4; ++i)
            gload_lds16(gB + (size_t)i * 16 * HIDDEN + k0, lB + i * 2048);

        // A: 16 dwordx4 loads + RTE casts -> av[2][4] (32 VGPR)
        half8 av[2][4];
        #pragma unroll
        for (int i = 0; i < 2; ++i)
            #pragma unroll
            for (int kk = 0; kk < 4; ++kk) {
                const float* p = gA + (size_t)i * 16 * HIDDEN + k0 + kk * 32;
                const float4 a = *reinterpret_cast<const float4*>(p);
                const float4 b = *reinterpret_cast<const float4*>(p + 4);
                half8 h;
                h[0] = (_Float16)a.x; h[1] = (_Float16)a.y;
                h[2] = (_Float16)a.z; h[3] = (_Float16)a.w;
                h[4] = (_Float16)b.x; h[5] = (_Float16)b.y;
                h[6] = (_Float16)b.z; h[7] = (_Float16)b.w;
                av[i][kk] = h;
            }
        __syncthreads();   // B tile ready (drain also covers A loads)

        #pragma unroll
        for (int kk = 0; kk < 4; ++kk) {
            half8 bv[4];
            #pragma unroll
            for (int j = 0; j < 4; ++j) {
                const int row = j * 16 + lr;
                const int off = (row * 128 + kk * 32 + lh * 8) ^ ((row & 7) << 3);
                bv[j] = *reinterpret_cast<const half8*>(&Bsm[off]);
            }
            #pragma unroll
            for (int i = 0; i < 2; ++i)
                #pragma unroll
                for (int j = 0; j < 4; ++j)
                    acc[i][j] = __builtin_amdgcn_mfma_f32_16x16x32_f16(
                        av[i][kk], bv[j], acc[i][j], 0, 0, 0);
        }
        __syncthreads();   // before next step's B overwrite
    }

    // ---- epilogue (identical to R10). C/D: col = lr + j*16,
    // row = wave*32 + i*16 + lh*4 + r
    if (ng < 4) {
        #pragma unroll
        for (int i = 0; i < 2; ++i)
            #pragma unroll
            for (int r = 0; r < 4; ++r) {
                const int m = m0 + wave * 32 + i * 16 + lh * 4 + r;
                const float x0 = acc[i][0][r], x1 = acc[i][1][r];
                const float c0 = cosb[(size_t)m * RR + lr];
                const float s0 = sinb[(size_t)m * RR + lr];
                const float c1 = cosb[(size_t)m * RR + 16 + lr];
                const float s1 = sinb[(size_t)m * RR + 16 + lr];
                const int sw = (m & 7) << 3;   // pre-swizzle for score staging
                const size_t rowb = (size_t)m * (NH * DD);
                const int e0 = ng * DD + lr;
                qout[rowb + (e0 ^ sw)]        = (_Float16)(x0 * c0 - x1 * s0);
                qout[rowb + ((e0 + 16) ^ sw)] = (_Float16)(x1 * c1 + x0 * s1);
                qout[rowb + ((e0 + 32) ^ sw)] = (_Float16)acc[i][2][r];
                qout[rowb + ((e0 + 48) ^ sw)] = (_Float16)acc[i][3][r];
            }
    } else if (ng == 4) {
        float g[4], bb[4];
        #pragma unroll
        for (int j = 0; j < 4; ++j) { g[j] = gamma[j * 16 + lr]; bb[j] = beta[j * 16 + lr]; }
        #pragma unroll
        for (int i = 0; i < 2; ++i)
            #pragma unroll
            for (int r = 0; r < 4; ++r) {
                float t1 = 0.f, t2 = 0.f;
                #pragma unroll
                for (int j = 0; j < 4; ++j) {
                    const float a = acc[i][j][r];
                    t1 += a; t2 += a * a;
                }
                #pragma unroll
                for (int msk = 1; msk < 16; msk <<= 1) {
                    t1 += __shfl_xor(t1, msk, 64);
                    t2 += __shfl_xor(t2, msk, 64);
                }
                const float mu  = t1 * (1.f / 64.f);
                const float var = t2 * (1.f / 64.f) - mu * mu;
                const float rs  = rsqrtf(var + LN_EPS);
                const int m = m0 + wave * 32 + i * 16 + lh * 4 + r;
                float x[4];
                #pragma unroll
                for (int j = 0; j < 4; ++j)
                    x[j] = (acc[i][j][r] - mu) * rs * g[j] + bb[j];
                const float c0 = cosb[(size_t)m * RR + lr];
                const float s0 = sinb[(size_t)m * RR + lr];
                const float c1 = cosb[(size_t)m * RR + 16 + lr];
                const float s1 = sinb[(size_t)m * RR + 16 + lr];
                const float y0 = x[0] * c0 - x[1] * s0;
                const float y1 = x[1] * c1 + x[0] * s1;
                const size_t base = (size_t)m * DD + lr;
                kout[base]      = (_Float16)y0;
                kout[base + 16] = (_Float16)y1;
                kout[base + 32] = (_Float16)x[2];
                kout[base + 48] = (_Float16)x[3];
            }
    } else {
        if (lr < NH) {
            #pragma unroll
            for (int i = 0; i < 2; ++i)
                #pragma unroll
                for (int r = 0; r < 4; ++r) {
                    const int m = m0 + wave * 32 + i * 16 + lh * 4 + r;
                    wout[(size_t)m * NH + lr] = acc[i][0][r];
                }
        }
    }
}

// ---------------------------------------------------------------------------
// score (R10 form, measured ~38 us): s = mfma(Q,K); C/D col=k, row=q; scalar
// stores (4 rows x 64B segments/inst). Pre-barrier first K-load + setprio
// kept (neutral, harmless). Grid (8 k-chunks, 64 q-tiles, B).
// ---------------------------------------------------------------------------
__global__ __launch_bounds__(256) void score_kernel(
    const _Float16* __restrict__ qb, const _Float16* __restrict__ kb,
    const float* __restrict__ wr, float* __restrict__ out)
{
    __shared__ _Float16 Qlds[64 * 256];   // 32 KB, swizzled slots
    __shared__ float Wlds[64 * 4];        // 1 KB

    const int kc  = blockIdx.x;          // 512-col k chunk
    const int q0  = blockIdx.y * 64;
    const int b   = blockIdx.z;
    const int tid = threadIdx.x;
    const int wave = tid >> 6, lane = tid & 63;
    const int wm = wave >> 1, wn = wave & 1;
    const int lr = lane & 15, lh = lane >> 4;
    const int kbase = kc * 512;

    #pragma unroll
    for (int i = 0; i < 8; ++i) {
        const int id = i * 256 + tid;
        gload_lds16(qb + (size_t)(b * SDIM + q0 + (id >> 5)) * 256 + (id & 31) * 8,
                    Qlds + id * 8);
    }
    Wlds[tid] = wr[(size_t)(b * SDIM + q0) * NH + tid];

    const size_t krow_base = (size_t)(b * SDIM + kbase + wn * 32);
    #define LOADK(dst, st)                                                      \
        _Pragma("unroll")                                                       \
        for (int j = 0; j < 2; ++j)                                             \
            _Pragma("unroll")                                                   \
            for (int ks = 0; ks < 2; ++ks)                                      \
                dst[j][ks] = *reinterpret_cast<const half8*>(                   \
                    &kb[(krow_base + (st) * 64 + j * 16 + lr) * DD + ks * 32 + lh * 8]);

    half8 kcur[2][2], knx[2][2];
    LOADK(kcur, 0)           // issued pre-barrier: overlaps Q-staging drain

    __syncthreads();

    f32x4 wreg[2][4];
    #pragma unroll
    for (int i = 0; i < 2; ++i)
        #pragma unroll
        for (int r = 0; r < 4; ++r)
            wreg[i][r] = *reinterpret_cast<const f32x4*>(
                &Wlds[(wm * 32 + i * 16 + lh * 4 + r) * 4]);

    for (int st = 0; st < 8; ++st) {
        if (st < 7) { LOADK(knx, st + 1) }

        f32x4 o[2][2];
        #pragma unroll
        for (int i = 0; i < 2; ++i)
            #pragma unroll
            for (int j = 0; j < 2; ++j)
                o[i][j] = (f32x4){0.f, 0.f, 0.f, 0.f};

        #pragma unroll
        for (int h = 0; h < NH; ++h) {
            half8 qf[2][2];
            #pragma unroll
            for (int i = 0; i < 2; ++i)
                #pragma unroll
                for (int ks = 0; ks < 2; ++ks) {
                    const int row  = wm * 32 + i * 16 + lr;
                    const int slot = (h * 8 + ks * 4 + lh) ^ (row & 7);
                    qf[i][ks] = *reinterpret_cast<const half8*>(
                        &Qlds[row * 256 + slot * 8]);
                }
            f32x4 s[2][2];
            #pragma unroll
            for (int i = 0; i < 2; ++i)
                #pragma unroll
                for (int j = 0; j < 2; ++j)
                    s[i][j] = (f32x4){0.f, 0.f, 0.f, 0.f};
            __builtin_amdgcn_s_setprio(1);
            #pragma unroll
            for (int ks = 0; ks < 2; ++ks)
                #pragma unroll
                for (int i = 0; i < 2; ++i)
                    #pragma unroll
                    for (int j = 0; j < 2; ++j)
                        s[i][j] = __builtin_amdgcn_mfma_f32_16x16x32_f16(
                            qf[i][ks], kcur[j][ks], s[i][j], 0, 0, 0);
            __builtin_amdgcn_s_setprio(0);
            #pragma unroll
            for (int i = 0; i < 2; ++i)
                #pragma unroll
                for (int j = 0; j < 2; ++j)
                    #pragma unroll
                    for (int r = 0; r < 4; ++r)
                        o[i][j][r] += wreg[i][r][h] * fmaxf(s[i][j][r], 0.f);
        }

        #pragma unroll
        for (int i = 0; i < 2; ++i)
            #pragma unroll
            for (int r = 0; r < 4; ++r)
                #pragma unroll
                for (int j = 0; j < 2; ++j)
                    out[(size_t)(b * SDIM + q0 + wm * 32 + i * 16 + lh * 4 + r) * SDIM
                        + kbase + st * 64 + wn * 32 + j * 16 + lr] = o[i][j][r];

        #pragma unroll
        for (int j = 0; j < 2; ++j)
            #pragma unroll
            for (int ks = 0; ks < 2; ++ks)
                kcur[j][ks] = knx[j][ks];
    }
    #undef LOADK
}

// ---------------------------------------------------------------------------
extern "C" void kernel_launch(void* const* d_in, const int* in_sizes, int n_in,
                              void* d_out, int out_size, void* d_ws, size_t ws_size,
                              hipStream_t stream) {
    const float* hs    = (const float*)d_in[0];
    const float* cosb  = (const float*)d_in[1];
    const float* sinb  = (const float*)d_in[2];
    const float* Wq    = (const float*)d_in[3];
    const float* Wk    = (const float*)d_in[4];
    const float* Ww    = (const float*)d_in[5];
    const float* gamma = (const float*)d_in[6];
    const float* beta  = (const float*)d_in[7];
    float* out = (float*)d_out;

    char* wsb = (char*)d_ws;
    _Float16* qb  = (_Float16*)wsb;                                   // [M,256] f16
    _Float16* kb  = (_Float16*)(wsb + (size_t)BDIM * SDIM * 256 * 2); // [M,64] f16
    float*    ww  = (float*)(wsb + (size_t)BDIM * SDIM * 256 * 2
                                  + (size_t)BDIM * SDIM * DD * 2);
    _Float16* Wt2 = (_Float16*)(wsb + (size_t)BDIM * SDIM * 256 * 2
                                     + (size_t)BDIM * SDIM * DD * 2
                                     + (size_t)BDIM * SDIM * NH * 4);

    prep_w2<<<dim3(HIDDEN / 64, 6), 256, 0, stream>>>(Wq, Wk, Ww, Wt2);

    proj_mfma<<<dim3((BDIM * SDIM) / 128, 6), 256, 0, stream>>>(
        hs, Wt2, cosb, sinb, gamma, beta, qb, kb, ww);

    score_kernel<<<dim3(SDIM / 512, SDIM / 64, BDIM), 256, 0, stream>>>(
        qb, kb, ww, out);
}

// Round 12
// 94.948 us; speedup vs baseline: 1.1838x; 1.1838x over previous
//
#include <hip/hip_runtime.h>

#define BDIM 2
#define SDIM 4096
#define HIDDEN 2048
#define NH 4
#define DD 64
#define RR 32
constexpr float LN_EPS = 1e-5f;

typedef _Float16 half8 __attribute__((ext_vector_type(8)));   // 8 f16 = 4 VGPRs
typedef __attribute__((ext_vector_type(4))) float f32x4;

// async global -> LDS, 16 B per lane (wave-uniform LDS base + lane*16)
__device__ __forceinline__ void gload_lds16(const void* g, void* l) {
    __builtin_amdgcn_global_load_lds(
        (const __attribute__((address_space(1))) void*)g,
        (__attribute__((address_space(3))) void*)l, 16, 0, 0);
}

// ---------------------------------------------------------------------------
// prep_split: fused split_hs + prep_w2 (one launch boundary saved).
// Blocks 0..8191: split_hs — hs f32 [M,2048] -> hs2 f16 [M,2048], pre-swizzled
//   per row (16B-slot XOR with m&7) for proj's linear gload_lds + XOR ds_read.
// Blocks 8192..8383: prep_w2 — Wt2 f16 [384][2048] transposed k-contiguous,
//   pre-swizzled. n-order: q 0..255, k 256..319, w 320..323, zeros to 383.
// ---------------------------------------------------------------------------
__global__ __launch_bounds__(256) void prep_split(
    const float* __restrict__ hs, _Float16* __restrict__ hs2,
    const float* __restrict__ Wq, const float* __restrict__ Wk,
    const float* __restrict__ Ww, _Float16* __restrict__ Wt2)
{
    __shared__ float T[64][65];
    const int tid = threadIdx.x;

    if (blockIdx.x < 8192) {
        const int idx  = blockIdx.x * 256 + tid;
        const int m    = idx >> 8;          // 256 slots per row
        const int slot = idx & 255;
        const float4 v0 = *reinterpret_cast<const float4*>(&hs[(size_t)m * HIDDEN + slot * 8]);
        const float4 v1 = *reinterpret_cast<const float4*>(&hs[(size_t)m * HIDDEN + slot * 8 + 4]);
        _Float16 o[8];
        o[0] = (_Float16)v0.x; o[1] = (_Float16)v0.y;
        o[2] = (_Float16)v0.z; o[3] = (_Float16)v0.w;
        o[4] = (_Float16)v1.x; o[5] = (_Float16)v1.y;
        o[6] = (_Float16)v1.z; o[7] = (_Float16)v1.w;
        const int eoff = (slot * 8) ^ ((m & 7) << 3);
        *reinterpret_cast<half8*>(&hs2[(size_t)m * HIDDEN + eoff]) =
            *reinterpret_cast<half8*>(o);
        return;
    }

    const int pb = blockIdx.x - 8192;       // 0..191
    const int k0 = (pb & 31) * 64;
    const int n0 = (pb >> 5) * 64;
    {
        const int kr = tid >> 2;
        const int nq = (tid & 3) * 16;
        const int gk = k0 + kr;
        #pragma unroll
        for (int c = 0; c < 16; ++c) {
            const int n = n0 + nq + c;
            float v;
            if (n < 256)      v = Wq[(size_t)gk * 256 + n];
            else if (n < 320) v = Wk[(size_t)gk * 64 + (n - 256)];
            else if (n < 324) v = Ww[(size_t)gk * NH + (n - 320)];
            else              v = 0.f;
            T[kr][nq + c] = v;
        }
    }
    __syncthreads();
    {
        const int nr = tid >> 2;
        const int kc = (tid & 3) * 16;
        const int n  = n0 + nr;
        #pragma unroll
        for (int s = 0; s < 2; ++s) {
            const int kb = kc + s * 8;
            _Float16 e[8];
            #pragma unroll
            for (int t = 0; t < 8; ++t) e[t] = (_Float16)T[kb + t][nr];
            const int eoff = (k0 + kb) ^ ((nr & 7) << 3);
            *reinterpret_cast<half8*>(&Wt2[(size_t)n * HIDDEN + eoff]) =
                *reinterpret_cast<half8*>(e);
        }
    }
}

// ---------------------------------------------------------------------------
// proj_mfma (R10 structure, measured 21 us): 128M x 64N, BK=128, K=2048,
// grid (64,6), 4 waves of 32M x 64N, 48 KB LDS -> 3 blocks/CU. q-epilogue
// writes qout PRE-SWIZZLED. k-epilogue writes kout at PERMUTED row
// (t&~31)|((t&1)<<4)|((t&31)>>1) so score's frag col j*16+lr = token 2lr+j
// -> thread's two outputs are adjacent global cols (dwordx2 store).
// ---------------------------------------------------------------------------
__global__ __launch_bounds__(256) void proj_mfma(
    const _Float16* __restrict__ hs2, const _Float16* __restrict__ Wt2,
    const float* __restrict__ cosb, const float* __restrict__ sinb,
    const float* __restrict__ gamma, const float* __restrict__ beta,
    _Float16* __restrict__ qout, _Float16* __restrict__ kout,
    float* __restrict__ wout)
{
    __shared__ _Float16 Asm[128 * 128];   // 32 KB
    __shared__ _Float16 Bsm[64 * 128];    // 16 KB

    const int m0   = blockIdx.x * 128;
    const int ng   = blockIdx.y;
    const int tid  = threadIdx.x;
    const int wave = tid >> 6, lane = tid & 63;
    const int lr = lane & 15, lh = lane >> 4;

    f32x4 acc[2][4];
    #pragma unroll
    for (int i = 0; i < 2; ++i)
        #pragma unroll
        for (int j = 0; j < 4; ++j)
            acc[i][j] = (f32x4){0.f, 0.f, 0.f, 0.f};

    const int srow  = tid >> 4;
    const int sslot = tid & 15;
    const _Float16* gA = hs2 + (size_t)(m0 + srow) * HIDDEN + sslot * 8;
    const _Float16* gB = Wt2 + (size_t)(ng * 64 + srow) * HIDDEN + sslot * 8;
    _Float16* lA = Asm + tid * 8;
    _Float16* lB = Bsm + tid * 8;

    for (int k0 = 0; k0 < HIDDEN; k0 += 128) {
        #pragma unroll
        for (int i = 0; i < 8; ++i)
            gload_lds16(gA + (size_t)i * 16 * HIDDEN + k0, lA + i * 2048);
        #pragma unroll
        for (int i = 0; i < 4; ++i)
            gload_lds16(gB + (size_t)i * 16 * HIDDEN + k0, lB + i * 2048);
        __syncthreads();

        #pragma unroll
        for (int kk = 0; kk < 4; ++kk) {
            half8 av[2], bv[4];
            #pragma unroll
            for (int i = 0; i < 2; ++i) {
                const int row = wave * 32 + i * 16 + lr;
                const int off = (row * 128 + kk * 32 + lh * 8) ^ ((row & 7) << 3);
                av[i] = *reinterpret_cast<const half8*>(&Asm[off]);
            }
            #pragma unroll
            for (int j = 0; j < 4; ++j) {
                const int row = j * 16 + lr;
                const int off = (row * 128 + kk * 32 + lh * 8) ^ ((row & 7) << 3);
                bv[j] = *reinterpret_cast<const half8*>(&Bsm[off]);
            }
            #pragma unroll
            for (int i = 0; i < 2; ++i)
                #pragma unroll
                for (int j = 0; j < 4; ++j)
                    acc[i][j] = __builtin_amdgcn_mfma_f32_16x16x32_f16(
                        av[i], bv[j], acc[i][j], 0, 0, 0);
        }
        __syncthreads();
    }

    // ---- epilogue. C/D: col = lr + j*16, row = wave*32 + i*16 + lh*4 + r
    if (ng < 4) {
        #pragma unroll
        for (int i = 0; i < 2; ++i)
            #pragma unroll
            for (int r = 0; r < 4; ++r) {
                const int m = m0 + wave * 32 + i * 16 + lh * 4 + r;
                const float x0 = acc[i][0][r], x1 = acc[i][1][r];
                const float c0 = cosb[(size_t)m * RR + lr];
                const float s0 = sinb[(size_t)m * RR + lr];
                const float c1 = cosb[(size_t)m * RR + 16 + lr];
                const float s1 = sinb[(size_t)m * RR + 16 + lr];
                const int sw = (m & 7) << 3;   // pre-swizzle for score staging
                const size_t rowb = (size_t)m * (NH * DD);
                const int e0 = ng * DD + lr;
                qout[rowb + (e0 ^ sw)]        = (_Float16)(x0 * c0 - x1 * s0);
                qout[rowb + ((e0 + 16) ^ sw)] = (_Float16)(x1 * c1 + x0 * s1);
                qout[rowb + ((e0 + 32) ^ sw)] = (_Float16)acc[i][2][r];
                qout[rowb + ((e0 + 48) ^ sw)] = (_Float16)acc[i][3][r];
            }
    } else if (ng == 4) {
        float g[4], bb[4];
        #pragma unroll
        for (int j = 0; j < 4; ++j) { g[j] = gamma[j * 16 + lr]; bb[j] = beta[j * 16 + lr]; }
        #pragma unroll
        for (int i = 0; i < 2; ++i)
            #pragma unroll
            for (int r = 0; r < 4; ++r) {
                float t1 = 0.f, t2 = 0.f;
                #pragma unroll
                for (int j = 0; j < 4; ++j) {
                    const float a = acc[i][j][r];
                    t1 += a; t2 += a * a;
                }
                #pragma unroll
                for (int msk = 1; msk < 16; msk <<= 1) {
                    t1 += __shfl_xor(t1, msk, 64);
                    t2 += __shfl_xor(t2, msk, 64);
                }
                const float mu  = t1 * (1.f / 64.f);
                const float var = t2 * (1.f / 64.f) - mu * mu;
                const float rs  = rsqrtf(var + LN_EPS);
                const int m = m0 + wave * 32 + i * 16 + lh * 4 + r;
                float x[4];
                #pragma unroll
                for (int j = 0; j < 4; ++j)
                    x[j] = (acc[i][j][r] - mu) * rs * g[j] + bb[j];
                const float c0 = cosb[(size_t)m * RR + lr];
                const float s0 = sinb[(size_t)m * RR + lr];
                const float c1 = cosb[(size_t)m * RR + 16 + lr];
                const float s1 = sinb[(size_t)m * RR + 16 + lr];
                const float y0 = x[0] * c0 - x[1] * s0;
                const float y1 = x[1] * c1 + x[0] * s1;
                // permuted storage row: token tok=m&31 -> f=((tok&1)<<4)|(tok>>1)
                const int tok  = m & 31;
                const int prow = (m & ~31) | ((tok & 1) << 4) | (tok >> 1);
                const size_t base = (size_t)prow * DD + lr;
                kout[base]      = (_Float16)y0;
                kout[base + 16] = (_Float16)y1;
                kout[base + 32] = (_Float16)x[2];
                kout[base + 48] = (_Float16)x[3];
            }
    } else {
        if (lr < NH) {
            #pragma unroll
            for (int i = 0; i < 2; ++i)
                #pragma unroll
                for (int r = 0; r < 4; ++r) {
                    const int m = m0 + wave * 32 + i * 16 + lh * 4 + r;
                    wout[(size_t)m * NH + lr] = acc[i][0][r];
                }
        }
    }
}

// ---------------------------------------------------------------------------
// score: s = mfma(Q,K); C/D col=k-frag-row, row=q. kb rows are PERMUTED so
// frag row j*16+lr = global token 2lr+j -> each thread's (j=0,j=1) pair is
// 2 adjacent cols: ONE dwordx2 store per (i,r) = 8 insts/subtile of 4x128B
// segments (vs 16 insts of 4x64B). LOADK physical pattern unchanged.
// ---------------------------------------------------------------------------
__global__ __launch_bounds__(256) void score_kernel(
    const _Float16* __restrict__ qb, const _Float16* __restrict__ kb,
    const float* __restrict__ wr, float* __restrict__ out)
{
    __shared__ _Float16 Qlds[64 * 256];   // 32 KB, swizzled slots
    __shared__ float Wlds[64 * 4];        // 1 KB

    const int kc  = blockIdx.x;          // 512-col k chunk
    const int q0  = blockIdx.y * 64;
    const int b   = blockIdx.z;
    const int tid = threadIdx.x;
    const int wave = tid >> 6, lane = tid & 63;
    const int wm = wave >> 1, wn = wave & 1;
    const int lr = lane & 15, lh = lane >> 4;
    const int kbase = kc * 512;

    #pragma unroll
    for (int i = 0; i < 8; ++i) {
        const int id = i * 256 + tid;
        gload_lds16(qb + (size_t)(b * SDIM + q0 + (id >> 5)) * 256 + (id & 31) * 8,
                    Qlds + id * 8);
    }
    Wlds[tid] = wr[(size_t)(b * SDIM + q0) * NH + tid];

    const size_t krow_base = (size_t)(b * SDIM + kbase + wn * 32);
    #define LOADK(dst, st)                                                      \
        _Pragma("unroll")                                                       \
        for (int j = 0; j < 2; ++j)                                             \
            _Pragma("unroll")                                                   \
            for (int ks = 0; ks < 2; ++ks)                                      \
                dst[j][ks] = *reinterpret_cast<const half8*>(                   \
                    &kb[(krow_base + (st) * 64 + j * 16 + lr) * DD + ks * 32 + lh * 8]);

    half8 kcur[2][2], knx[2][2];
    LOADK(kcur, 0)           // issued pre-barrier: overlaps Q-staging drain

    __syncthreads();

    f32x4 wreg[2][4];
    #pragma unroll
    for (int i = 0; i < 2; ++i)
        #pragma unroll
        for (int r = 0; r < 4; ++r)
            wreg[i][r] = *reinterpret_cast<const f32x4*>(
                &Wlds[(wm * 32 + i * 16 + lh * 4 + r) * 4]);

    for (int st = 0; st < 8; ++st) {
        if (st < 7) { LOADK(knx, st + 1) }

        f32x4 o[2][2];
        #pragma unroll
        for (int i = 0; i < 2; ++i)
            #pragma unroll
            for (int j = 0; j < 2; ++j)
                o[i][j] = (f32x4){0.f, 0.f, 0.f, 0.f};

        #pragma unroll
        for (int h = 0; h < NH; ++h) {
            half8 qf[2][2];
            #pragma unroll
            for (int i = 0; i < 2; ++i)
                #pragma unroll
                for (int ks = 0; ks < 2; ++ks) {
                    const int row  = wm * 32 + i * 16 + lr;
                    const int slot = (h * 8 + ks * 4 + lh) ^ (row & 7);
                    qf[i][ks] = *reinterpret_cast<const half8*>(
                        &Qlds[row * 256 + slot * 8]);
                }
            f32x4 s[2][2];
            #pragma unroll
            for (int i = 0; i < 2; ++i)
                #pragma unroll
                for (int j = 0; j < 2; ++j)
                    s[i][j] = (f32x4){0.f, 0.f, 0.f, 0.f};
            __builtin_amdgcn_s_setprio(1);
            #pragma unroll
            for (int ks = 0; ks < 2; ++ks)
                #pragma unroll
                for (int i = 0; i < 2; ++i)
                    #pragma unroll
                    for (int j = 0; j < 2; ++j)
                        s[i][j] = __builtin_amdgcn_mfma_f32_16x16x32_f16(
                            qf[i][ks], kcur[j][ks], s[i][j], 0, 0, 0);
            __builtin_amdgcn_s_setprio(0);
            #pragma unroll
            for (int i = 0; i < 2; ++i)
                #pragma unroll
                for (int j = 0; j < 2; ++j)
                    #pragma unroll
                    for (int r = 0; r < 4; ++r)
                        o[i][j][r] += wreg[i][r][h] * fmaxf(s[i][j][r], 0.f);
        }

        // dwordx2 stores: thread holds tokens 2lr, 2lr+1 (permuted kb)
        #pragma unroll
        for (int i = 0; i < 2; ++i)
            #pragma unroll
            for (int r = 0; r < 4; ++r) {
                float2 v;
                v.x = o[i][0][r]; v.y = o[i][1][r];
                *reinterpret_cast<float2*>(
                    &out[(size_t)(b * SDIM + q0 + wm * 32 + i * 16 + lh * 4 + r) * SDIM
                        + kbase + st * 64 + wn * 32 + 2 * lr]) = v;
            }

        #pragma unroll
        for (int j = 0; j < 2; ++j)
            #pragma unroll
            for (int ks = 0; ks < 2; ++ks)
                kcur[j][ks] = knx[j][ks];
    }
    #undef LOADK
}

// ---------------------------------------------------------------------------
extern "C" void kernel_launch(void* const* d_in, const int* in_sizes, int n_in,
                              void* d_out, int out_size, void* d_ws, size_t ws_size,
                              hipStream_t stream) {
    const float* hs    = (const float*)d_in[0];
    const float* cosb  = (const float*)d_in[1];
    const float* sinb  = (const float*)d_in[2];
    const float* Wq    = (const float*)d_in[3];
    const float* Wk    = (const float*)d_in[4];
    const float* Ww    = (const float*)d_in[5];
    const float* gamma = (const float*)d_in[6];
    const float* beta  = (const float*)d_in[7];
    float* out = (float*)d_out;

    // hs2 (33.5 MB f16) lives in d_out; dead after proj, overwritten by score.
    _Float16* hs2 = (_Float16*)d_out;

    char* wsb = (char*)d_ws;
    _Float16* qb  = (_Float16*)wsb;                                   // [M,256] f16
    _Float16* kb  = (_Float16*)(wsb + (size_t)BDIM * SDIM * 256 * 2); // [M,64] f16
    float*    ww  = (float*)(wsb + (size_t)BDIM * SDIM * 256 * 2
                                  + (size_t)BDIM * SDIM * DD * 2);
    _Float16* Wt2 = (_Float16*)(wsb + (size_t)BDIM * SDIM * 256 * 2
                                     + (size_t)BDIM * SDIM * DD * 2
                                     + (size_t)BDIM * SDIM * NH * 4);

    prep_split<<<8192 + 192, 256, 0, stream>>>(hs, hs2, Wq, Wk, Ww, Wt2);

    proj_mfma<<<dim3((BDIM * SDIM) / 128, 6), 256, 0, stream>>>(
        hs2, Wt2, cosb, sinb, gamma, beta, qb, kb, ww);

    score_kernel<<<dim3(SDIM / 512, SDIM / 64, BDIM), 256, 0, stream>>>(
        qb, kb, ww, out);
}

// Round 14
// 84.909 us; speedup vs baseline: 1.3238x; 1.1182x over previous
//
#include <hip/hip_runtime.h>

#define BDIM 2
#define SDIM 4096
#define HIDDEN 2048
#define NH 4
#define DD 64
#define RR 32
constexpr float LN_EPS = 1e-5f;

typedef _Float16 half8 __attribute__((ext_vector_type(8)));   // 8 f16 = 4 VGPRs
typedef __attribute__((ext_vector_type(4))) float f32x4;

// async global -> LDS, 16 B per lane (wave-uniform LDS base + lane*16)
__device__ __forceinline__ void gload_lds16(const void* g, void* l) {
    __builtin_amdgcn_global_load_lds(
        (const __attribute__((address_space(1))) void*)g,
        (__attribute__((address_space(3))) void*)l, 16, 0, 0);
}

// ---------------------------------------------------------------------------
// split_hs: hs f32 [M,2048] -> hs2 f16 [M,2048], pre-swizzled per row
// (16B-slot XOR with m&7) so linear global_load_lds + XOR ds_read is
// conflict-free (rule #21). One thread per 8-elem slot. M = 8192.
// ---------------------------------------------------------------------------
__global__ __launch_bounds__(256) void split_hs(
    const float* __restrict__ hs, _Float16* __restrict__ hs2)
{
    const int idx  = blockIdx.x * 256 + threadIdx.x;
    const int m    = idx >> 8;          // 256 slots per row
    const int slot = idx & 255;
    const float4 v0 = *reinterpret_cast<const float4*>(&hs[(size_t)m * HIDDEN + slot * 8]);
    const float4 v1 = *reinterpret_cast<const float4*>(&hs[(size_t)m * HIDDEN + slot * 8 + 4]);
    _Float16 o[8];
    o[0] = (_Float16)v0.x; o[1] = (_Float16)v0.y;
    o[2] = (_Float16)v0.z; o[3] = (_Float16)v0.w;
    o[4] = (_Float16)v1.x; o[5] = (_Float16)v1.y;
    o[6] = (_Float16)v1.z; o[7] = (_Float16)v1.w;
    const int eoff = (slot * 8) ^ ((m & 7) << 3);
    *reinterpret_cast<half8*>(&hs2[(size_t)m * HIDDEN + eoff]) =
        *reinterpret_cast<half8*>(o);
}

// ---------------------------------------------------------------------------
// prep_w2 (R6 map): Wt2 f16 [384][2048] transposed k-contiguous, pre-swizzled.
// n-order: q 0..255, k 256..319, w 320..323, zeros to 383. Grid (32, 6).
// ---------------------------------------------------------------------------
__global__ __launch_bounds__(256) void prep_w2(
    const float* __restrict__ Wq, const float* __restrict__ Wk,
    const float* __restrict__ Ww, _Float16* __restrict__ Wt2)
{
    __shared__ float T[64][65];
    const int k0 = blockIdx.x * 64, n0 = blockIdx.y * 64;
    const int tid = threadIdx.x;
    {
        const int kr = tid >> 2;
        const int nq = (tid & 3) * 16;
        const int gk = k0 + kr;
        #pragma unroll
        for (int c = 0; c < 16; ++c) {
            const int n = n0 + nq + c;
            float v;
            if (n < 256)      v = Wq[(size_t)gk * 256 + n];
            else if (n < 320) v = Wk[(size_t)gk * 64 + (n - 256)];
            else if (n < 324) v = Ww[(size_t)gk * NH + (n - 320)];
            else              v = 0.f;
            T[kr][nq + c] = v;
        }
    }
    __syncthreads();
    {
        const int nr = tid >> 2;
        const int kc = (tid & 3) * 16;
        const int n  = n0 + nr;
        #pragma unroll
        for (int s = 0; s < 2; ++s) {
            const int kb = kc + s * 8;
            _Float16 e[8];
            #pragma unroll
            for (int t = 0; t < 8; ++t) e[t] = (_Float16)T[kb + t][nr];
            const int eoff = (k0 + kb) ^ ((nr & 7) << 3);
            *reinterpret_cast<half8*>(&Wt2[(size_t)n * HIDDEN + eoff]) =
                *reinterpret_cast<half8*>(e);
        }
    }
}

// ---------------------------------------------------------------------------
// proj_mfma (R6/R10 structure, measured 21 us): 128M x 64N, BK=128, K=2048,
// grid (64,6), 4 waves of 32M x 64N, 48 KB LDS -> 3 blocks/CU (the occupancy
// that hides the pre-barrier vmcnt drain). q-epilogue writes qout PRE-SWIZZLED.
// ---------------------------------------------------------------------------
__global__ __launch_bounds__(256) void proj_mfma(
    const _Float16* __restrict__ hs2, const _Float16* __restrict__ Wt2,
    const float* __restrict__ cosb, const float* __restrict__ sinb,
    const float* __restrict__ gamma, const float* __restrict__ beta,
    _Float16* __restrict__ qout, _Float16* __restrict__ kout,
    float* __restrict__ wout)
{
    __shared__ _Float16 Asm[128 * 128];   // 32 KB
    __shared__ _Float16 Bsm[64 * 128];    // 16 KB

    const int m0   = blockIdx.x * 128;
    const int ng   = blockIdx.y;
    const int tid  = threadIdx.x;
    const int wave = tid >> 6, lane = tid & 63;
    const int lr = lane & 15, lh = lane >> 4;

    f32x4 acc[2][4];
    #pragma unroll
    for (int i = 0; i < 2; ++i)
        #pragma unroll
        for (int j = 0; j < 4; ++j)
            acc[i][j] = (f32x4){0.f, 0.f, 0.f, 0.f};

    const int srow  = tid >> 4;
    const int sslot = tid & 15;
    const _Float16* gA = hs2 + (size_t)(m0 + srow) * HIDDEN + sslot * 8;
    const _Float16* gB = Wt2 + (size_t)(ng * 64 + srow) * HIDDEN + sslot * 8;
    _Float16* lA = Asm + tid * 8;
    _Float16* lB = Bsm + tid * 8;

    for (int k0 = 0; k0 < HIDDEN; k0 += 128) {
        #pragma unroll
        for (int i = 0; i < 8; ++i)
            gload_lds16(gA + (size_t)i * 16 * HIDDEN + k0, lA + i * 2048);
        #pragma unroll
        for (int i = 0; i < 4; ++i)
            gload_lds16(gB + (size_t)i * 16 * HIDDEN + k0, lB + i * 2048);
        __syncthreads();

        #pragma unroll
        for (int kk = 0; kk < 4; ++kk) {
            half8 av[2], bv[4];
            #pragma unroll
            for (int i = 0; i < 2; ++i) {
                const int row = wave * 32 + i * 16 + lr;
                const int off = (row * 128 + kk * 32 + lh * 8) ^ ((row & 7) << 3);
                av[i] = *reinterpret_cast<const half8*>(&Asm[off]);
            }
            #pragma unroll
            for (int j = 0; j < 4; ++j) {
                const int row = j * 16 + lr;
                const int off = (row * 128 + kk * 32 + lh * 8) ^ ((row & 7) << 3);
                bv[j] = *reinterpret_cast<const half8*>(&Bsm[off]);
            }
            #pragma unroll
            for (int i = 0; i < 2; ++i)
                #pragma unroll
                for (int j = 0; j < 4; ++j)
                    acc[i][j] = __builtin_amdgcn_mfma_f32_16x16x32_f16(
                        av[i], bv[j], acc[i][j], 0, 0, 0);
        }
        __syncthreads();
    }

    // ---- epilogue. C/D: col = lr + j*16, row = wave*32 + i*16 + lh*4 + r
    if (ng < 4) {
        #pragma unroll
        for (int i = 0; i < 2; ++i)
            #pragma unroll
            for (int r = 0; r < 4; ++r) {
                const int m = m0 + wave * 32 + i * 16 + lh * 4 + r;
                const float x0 = acc[i][0][r], x1 = acc[i][1][r];
                const float c0 = cosb[(size_t)m * RR + lr];
                const float s0 = sinb[(size_t)m * RR + lr];
                const float c1 = cosb[(size_t)m * RR + 16 + lr];
                const float s1 = sinb[(size_t)m * RR + 16 + lr];
                const int sw = (m & 7) << 3;   // pre-swizzle for score staging
                const size_t rowb = (size_t)m * (NH * DD);
                const int e0 = ng * DD + lr;
                qout[rowb + (e0 ^ sw)]        = (_Float16)(x0 * c0 - x1 * s0);
                qout[rowb + ((e0 + 16) ^ sw)] = (_Float16)(x1 * c1 + x0 * s1);
                qout[rowb + ((e0 + 32) ^ sw)] = (_Float16)acc[i][2][r];
                qout[rowb + ((e0 + 48) ^ sw)] = (_Float16)acc[i][3][r];
            }
    } else if (ng == 4) {
        float g[4], bb[4];
        #pragma unroll
        for (int j = 0; j < 4; ++j) { g[j] = gamma[j * 16 + lr]; bb[j] = beta[j * 16 + lr]; }
        #pragma unroll
        for (int i = 0; i < 2; ++i)
            #pragma unroll
            for (int r = 0; r < 4; ++r) {
                float t1 = 0.f, t2 = 0.f;
                #pragma unroll
                for (int j = 0; j < 4; ++j) {
                    const float a = acc[i][j][r];
                    t1 += a; t2 += a * a;
                }
                #pragma unroll
                for (int msk = 1; msk < 16; msk <<= 1) {
                    t1 += __shfl_xor(t1, msk, 64);
                    t2 += __shfl_xor(t2, msk, 64);
                }
                const float mu  = t1 * (1.f / 64.f);
                const float var = t2 * (1.f / 64.f) - mu * mu;
                const float rs  = rsqrtf(var + LN_EPS);
                const int m = m0 + wave * 32 + i * 16 + lh * 4 + r;
                float x[4];
                #pragma unroll
                for (int j = 0; j < 4; ++j)
                    x[j] = (acc[i][j][r] - mu) * rs * g[j] + bb[j];
                const float c0 = cosb[(size_t)m * RR + lr];
                const float s0 = sinb[(size_t)m * RR + lr];
                const float c1 = cosb[(size_t)m * RR + 16 + lr];
                const float s1 = sinb[(size_t)m * RR + 16 + lr];
                const float y0 = x[0] * c0 - x[1] * s0;
                const float y1 = x[1] * c1 + x[0] * s1;
                const size_t base = (size_t)m * DD + lr;
                kout[base]      = (_Float16)y0;
                kout[base + 16] = (_Float16)y1;
                kout[base + 32] = (_Float16)x[2];
                kout[base + 48] = (_Float16)x[3];
            }
    } else {
        if (lr < NH) {
            #pragma unroll
            for (int i = 0; i < 2; ++i)
                #pragma unroll
                for (int r = 0; r < 4; ++r) {
                    const int m = m0 + wave * 32 + i * 16 + lh * 4 + r;
                    wout[(size_t)m * NH + lr] = acc[i][0][r];
                }
        }
    }
}

// ---------------------------------------------------------------------------
// score (R10 form, measured ~38 us): s = mfma(Q,K); C/D col=k, row=q; scalar
// stores (4 rows x 64B segments/inst — three alternative store layouts all
// measured worse: R7 dwordx4-k-major, R12 permuted dwordx2). Pre-barrier
// first K-load + setprio kept (neutral, harmless).
// ---------------------------------------------------------------------------
__global__ __launch_bounds__(256) void score_kernel(
    const _Float16* __restrict__ qb, const _Float16* __restrict__ kb,
    const float* __restrict__ wr, float* __restrict__ out)
{
    __shared__ _Float16 Qlds[64 * 256];   // 32 KB, swizzled slots
    __shared__ float Wlds[64 * 4];        // 1 KB

    const int kc  = blockIdx.x;          // 512-col k chunk
    const int q0  = blockIdx.y * 64;
    const int b   = blockIdx.z;
    const int tid = threadIdx.x;
    const int wave = tid >> 6, lane = tid & 63;
    const int wm = wave >> 1, wn = wave & 1;
    const int lr = lane & 15, lh = lane >> 4;
    const int kbase = kc * 512;

    #pragma unroll
    for (int i = 0; i < 8; ++i) {
        const int id = i * 256 + tid;
        gload_lds16(qb + (size_t)(b * SDIM + q0 + (id >> 5)) * 256 + (id & 31) * 8,
                    Qlds + id * 8);
    }
    Wlds[tid] = wr[(size_t)(b * SDIM + q0) * NH + tid];

    const size_t krow_base = (size_t)(b * SDIM + kbase + wn * 32);
    #define LOADK(dst, st)                                                      \
        _Pragma("unroll")                                                       \
        for (int j = 0; j < 2; ++j)                                             \
            _Pragma("unroll")                                                   \
            for (int ks = 0; ks < 2; ++ks)                                      \
                dst[j][ks] = *reinterpret_cast<const half8*>(                   \
                    &kb[(krow_base + (st) * 64 + j * 16 + lr) * DD + ks * 32 + lh * 8]);

    half8 kcur[2][2], knx[2][2];
    LOADK(kcur, 0)           // issued pre-barrier: overlaps Q-staging drain

    __syncthreads();

    f32x4 wreg[2][4];
    #pragma unroll
    for (int i = 0; i < 2; ++i)
        #pragma unroll
        for (int r = 0; r < 4; ++r)
            wreg[i][r] = *reinterpret_cast<const f32x4*>(
                &Wlds[(wm * 32 + i * 16 + lh * 4 + r) * 4]);

    for (int st = 0; st < 8; ++st) {
        if (st < 7) { LOADK(knx, st + 1) }

        f32x4 o[2][2];
        #pragma unroll
        for (int i = 0; i < 2; ++i)
            #pragma unroll
            for (int j = 0; j < 2; ++j)
                o[i][j] = (f32x4){0.f, 0.f, 0.f, 0.f};

        #pragma unroll
        for (int h = 0; h < NH; ++h) {
            half8 qf[2][2];
            #pragma unroll
            for (int i = 0; i < 2; ++i)
                #pragma unroll
                for (int ks = 0; ks < 2; ++ks) {
                    const int row  = wm * 32 + i * 16 + lr;
                    const int slot = (h * 8 + ks * 4 + lh) ^ (row & 7);
                    qf[i][ks] = *reinterpret_cast<const half8*>(
                        &Qlds[row * 256 + slot * 8]);
                }
            f32x4 s[2][2];
            #pragma unroll
            for (int i = 0; i < 2; ++i)
                #pragma unroll
                for (int j = 0; j < 2; ++j)
                    s[i][j] = (f32x4){0.f, 0.f, 0.f, 0.f};
            __builtin_amdgcn_s_setprio(1);
            #pragma unroll
            for (int ks = 0; ks < 2; ++ks)
                #pragma unroll
                for (int i = 0; i < 2; ++i)
                    #pragma unroll
                    for (int j = 0; j < 2; ++j)
                        s[i][j] = __builtin_amdgcn_mfma_f32_16x16x32_f16(
                            qf[i][ks], kcur[j][ks], s[i][j], 0, 0, 0);
            __builtin_amdgcn_s_setprio(0);
            #pragma unroll
            for (int i = 0; i < 2; ++i)
                #pragma unroll
                for (int j = 0; j < 2; ++j)
                    #pragma unroll
                    for (int r = 0; r < 4; ++r)
                        o[i][j][r] += wreg[i][r][h] * fmaxf(s[i][j][r], 0.f);
        }

        #pragma unroll
        for (int i = 0; i < 2; ++i)
            #pragma unroll
            for (int r = 0; r < 4; ++r)
                #pragma unroll
                for (int j = 0; j < 2; ++j)
                    out[(size_t)(b * SDIM + q0 + wm * 32 + i * 16 + lh * 4 + r) * SDIM
                        + kbase + st * 64 + wn * 32 + j * 16 + lr] = o[i][j][r];

        #pragma unroll
        for (int j = 0; j < 2; ++j)
            #pragma unroll
            for (int ks = 0; ks < 2; ++ks)
                kcur[j][ks] = knx[j][ks];
    }
    #undef LOADK
}

// ---------------------------------------------------------------------------
extern "C" void kernel_launch(void* const* d_in, const int* in_sizes, int n_in,
                              void* d_out, int out_size, void* d_ws, size_t ws_size,
                              hipStream_t stream) {
    const float* hs    = (const float*)d_in[0];
    const float* cosb  = (const float*)d_in[1];
    const float* sinb  = (const float*)d_in[2];
    const float* Wq    = (const float*)d_in[3];
    const float* Wk    = (const float*)d_in[4];
    const float* Ww    = (const float*)d_in[5];
    const float* gamma = (const float*)d_in[6];
    const float* beta  = (const float*)d_in[7];
    float* out = (float*)d_out;

    // hs2 (33.5 MB f16) lives in d_out; dead after proj, overwritten by score.
    _Float16* hs2 = (_Float16*)d_out;

    char* wsb = (char*)d_ws;
    _Float16* qb  = (_Float16*)wsb;                                   // [M,256] f16
    _Float16* kb  = (_Float16*)(wsb + (size_t)BDIM * SDIM * 256 * 2); // [M,64] f16
    float*    ww  = (float*)(wsb + (size_t)BDIM * SDIM * 256 * 2
                                  + (size_t)BDIM * SDIM * DD * 2);
    _Float16* Wt2 = (_Float16*)(wsb + (size_t)BDIM * SDIM * 256 * 2
                                     + (size_t)BDIM * SDIM * DD * 2
                                     + (size_t)BDIM * SDIM * NH * 4);

    prep_w2<<<dim3(HIDDEN / 64, 6), 256, 0, stream>>>(Wq, Wk, Ww, Wt2);

    split_hs<<<(BDIM * SDIM * (HIDDEN / 8)) / 256, 256, 0, stream>>>(hs, hs2);

    proj_mfma<<<dim3((BDIM * SDIM) / 128, 6), 256, 0, stream>>>(
        hs2, Wt2, cosb, sinb, gamma, beta, qb, kb, ww);

    score_kernel<<<dim3(SDIM / 512, SDIM / 64, BDIM), 256, 0, stream>>>(
        qb, kb, ww, out);
}